// Round 1
// baseline (768.467 us; speedup 1.0000x reference)
//
#include <hip/hip_runtime.h>
#include <math.h>

#define PI_F 3.14159265358979323846f

// Problem constants (fixed by reference):
// x:[16][64][256][256] f32, weights ×4:[64][64][32][32] f32, out:[16][64][256][256] f32
// modes: ky m=0..63 -> ky = m (m<32) else m+192 ; kx = 0..31
//
// Pipeline (separable pruned DFTs; all scratch except tables+Y1 lives in d_out):
//   A: A1[bi][h][64] = x-DFT  (cols 0..31 = Re = sum x*cos, 32..63 = Im = sum x*(-sin))
//   B: X2[bi][mode]  = y-DFT over h (conj twiddle), mode = m*32+kx, float2
//   C: Cc[b*64+o][mode] = sum_i X2 * W  (complex), * c_kx/65536
//   D: Y1[bo][h][64] = inverse-y; cols 0..31 = Re, 32..63 = -Im
//   E: out[row][w]   = dot(Y1row[64], twxT[:, w])   (cos rows | sin rows)

static constexpr int T_TWXA = 0;        // [256 w][64]   cos | -sin   (fwd x)
static constexpr int T_TWYB = 16384;    // [256 h][128]  cos[64] | sin[64] at ky(m)
static constexpr int T_TWYT = 49152;    // [2][64 m][256 h]  cos plane, sin plane
static constexpr int T_TWXT = 81920;    // [64][256]     rows 0..31 cos, 32..63 sin
static constexpr int T_Y1   = 98304;    // [1024 bo][256 h][64]

// ---------------- twiddle tables ----------------
__global__ __launch_bounds__(256) void k_prep(float* __restrict__ ws) {
  int idx = blockIdx.x * 256 + threadIdx.x;
  if (idx < 16384) {
    int w = idx >> 6, col = idx & 63, k = col & 31;
    float ang = (2.0f * PI_F / 256.0f) * (float)((k * w) & 255);
    ws[T_TWXA + idx] = (col < 32) ? cosf(ang) : -sinf(ang);
  } else if (idx < 49152) {
    int j = idx - 16384;
    int h = j >> 7, col = j & 127, m = col & 63;
    int ky = (m < 32) ? m : (m + 192);
    float ang = (2.0f * PI_F / 256.0f) * (float)((ky * h) & 255);
    ws[idx] = (col < 64) ? cosf(ang) : sinf(ang);
  } else if (idx < 81920) {
    int j = idx - 49152;
    int part = j >> 14, m = (j >> 8) & 63, h = j & 255;
    int ky = (m < 32) ? m : (m + 192);
    float ang = (2.0f * PI_F / 256.0f) * (float)((ky * h) & 255);
    ws[idx] = part ? sinf(ang) : cosf(ang);
  } else if (idx < 98304) {
    int j = idx - 81920;
    int row = j >> 8, w = j & 255, k = row & 31;
    float ang = (2.0f * PI_F / 256.0f) * (float)((k * w) & 255);
    ws[idx] = (row < 32) ? cosf(ang) : sinf(ang);
  }
}

// ---------------- A: forward x-DFT ----------------
// grid 8192 = 1024 (b*64+i) × 8 h-tiles of 32 rows; block 256
__global__ __launch_bounds__(256) void k_A(const float* __restrict__ x,
                                           const float* __restrict__ twxA,
                                           float* __restrict__ A1) {
  __shared__ float xs[32][260];   // pad 260: banks (4r+k)%32, conflict-free
  const int t = threadIdx.x;
  const int blk = blockIdx.x;
  const int ht = blk & 7;
  const int bi = blk >> 3;
  const float4* xp = (const float4*)(x + (size_t)bi * 65536 + (size_t)ht * 8192);
#pragma unroll
  for (int j = 0; j < 8; ++j) {
    int f4 = t + 256 * j;
    int r = f4 >> 6, c4 = f4 & 63;
    *((float4*)&xs[r][c4 * 4]) = xp[f4];
  }
  __syncthreads();
  const int cg = t & 15, rg = t >> 4;   // 4 cols (cg*4..), 2 rows (rg*2..)
  float a00 = 0.f, a01 = 0.f, a02 = 0.f, a03 = 0.f;
  float a10 = 0.f, a11 = 0.f, a12 = 0.f, a13 = 0.f;
  const float4* twp = (const float4*)twxA;
#pragma unroll 4
  for (int k = 0; k < 256; ++k) {
    float4 c = twp[k * 16 + cg];      // L1-resident 64 KB table
    float x0 = xs[rg * 2 + 0][k];
    float x1 = xs[rg * 2 + 1][k];
    a00 = fmaf(x0, c.x, a00); a01 = fmaf(x0, c.y, a01);
    a02 = fmaf(x0, c.z, a02); a03 = fmaf(x0, c.w, a03);
    a10 = fmaf(x1, c.x, a10); a11 = fmaf(x1, c.y, a11);
    a12 = fmaf(x1, c.z, a12); a13 = fmaf(x1, c.w, a13);
  }
  size_t base = (size_t)bi * 16384 + (size_t)(ht * 32 + rg * 2) * 64 + cg * 4;
  *((float4*)(A1 + base))      = make_float4(a00, a01, a02, a03);
  *((float4*)(A1 + base + 64)) = make_float4(a10, a11, a12, a13);
}

// ---------------- B: forward y-DFT ----------------
// grid 1024 (b*64+i); block 256: thread = (m = t>>2, kx0 = (t&3)*8)
__global__ __launch_bounds__(256) void k_B(const float* __restrict__ A1,
                                           const float* __restrict__ twyB,
                                           float2* __restrict__ X2) {
  __shared__ float as[64][68];
  const int t = threadIdx.x, bi = blockIdx.x;
  const int m = t >> 2, kx0 = (t & 3) * 8;
  float accr[8] = {0,0,0,0,0,0,0,0};
  float acci[8] = {0,0,0,0,0,0,0,0};
  const float* Ap = A1 + (size_t)bi * 16384;
  for (int hc = 0; hc < 4; ++hc) {
    __syncthreads();
    const float4* src = (const float4*)(Ap + hc * 4096);
#pragma unroll
    for (int j = 0; j < 4; ++j) {
      int f4 = t + 256 * j;
      int r = f4 >> 4, c4 = f4 & 15;
      *((float4*)&as[r][c4 * 4]) = src[f4];
    }
    __syncthreads();
    const float* ty = twyB + hc * 64 * 128;
#pragma unroll 2
    for (int h = 0; h < 64; ++h) {
      float cy = ty[h * 128 + m];
      float sy = ty[h * 128 + 64 + m];
      float4 r0 = *((const float4*)&as[h][kx0]);
      float4 r1 = *((const float4*)&as[h][kx0 + 4]);
      float4 i0 = *((const float4*)&as[h][32 + kx0]);
      float4 i1 = *((const float4*)&as[h][32 + kx0 + 4]);
      // (Ar + iAi) * (cy - i sy):  re = Ar*cy + Ai*sy ; im = Ai*cy - Ar*sy
#define CMAC_B(j, rr, ii)                                   \
      accr[j] = fmaf(rr, cy, fmaf(ii, sy, accr[j]));        \
      acci[j] = fmaf(ii, cy, fmaf(-(rr), sy, acci[j]));
      CMAC_B(0, r0.x, i0.x) CMAC_B(1, r0.y, i0.y)
      CMAC_B(2, r0.z, i0.z) CMAC_B(3, r0.w, i0.w)
      CMAC_B(4, r1.x, i1.x) CMAC_B(5, r1.y, i1.y)
      CMAC_B(6, r1.z, i1.z) CMAC_B(7, r1.w, i1.w)
#undef CMAC_B
    }
  }
  float2* dst = X2 + (size_t)bi * 2048 + m * 32 + kx0;
  float4* d4 = (float4*)dst;
  d4[0] = make_float4(accr[0], acci[0], accr[1], acci[1]);
  d4[1] = make_float4(accr[2], acci[2], accr[3], acci[3]);
  d4[2] = make_float4(accr[4], acci[4], accr[5], acci[5]);
  d4[3] = make_float4(accr[6], acci[6], accr[7], acci[7]);
}

// ---------------- C: channel mix ----------------
// grid 512 = 32 mode-chunks(64) × 2 b-tiles(8) × 8 o-tiles(8); block 256
__global__ __launch_bounds__(256) void k_C(const float2* __restrict__ X2,
                                           const float* __restrict__ wpr,
                                           const float* __restrict__ wpi,
                                           const float* __restrict__ wnr,
                                           const float* __restrict__ wni,
                                           float2* __restrict__ Cc) {
  __shared__ float Xr[8][65], Xi[8][65], Wr[8][65], Wi[8][65];
  const int t = threadIdx.x, blk = blockIdx.x;
  const int mc = blk >> 4, bt = (blk >> 3) & 1, ot = blk & 7;
  const int mode0 = mc * 64, b0 = bt * 8, o0 = ot * 8;
  const float* wr; const float* wi; int wm0;
  if (mode0 < 1024) { wr = wpr; wi = wpi; wm0 = mode0; }
  else              { wr = wnr; wi = wni; wm0 = mode0 - 1024; }
  const int md = t & 63, grp = t >> 6;    // thread: mode md, b-pair grp*2..
  float accr0[8] = {0,0,0,0,0,0,0,0};
  float acci0[8] = {0,0,0,0,0,0,0,0};
  float accr1[8] = {0,0,0,0,0,0,0,0};
  float acci1[8] = {0,0,0,0,0,0,0,0};
  for (int i = 0; i < 64; ++i) {
    __syncthreads();
#pragma unroll
    for (int j = 0; j < 2; ++j) {
      int idx = t + 256 * j;
      int r = idx >> 6, mm = idx & 63;
      float2 v = X2[((size_t)(b0 + r) * 64 + i) * 2048 + mode0 + mm];
      Xr[r][mm] = v.x; Xi[r][mm] = v.y;
      size_t wo = ((size_t)i * 64 + (o0 + r)) * 1024 + wm0 + mm;
      Wr[r][mm] = wr[wo]; Wi[r][mm] = wi[wo];
    }
    __syncthreads();
    float xr0 = Xr[grp * 2 + 0][md], xi0 = Xi[grp * 2 + 0][md];
    float xr1 = Xr[grp * 2 + 1][md], xi1 = Xi[grp * 2 + 1][md];
#pragma unroll
    for (int o = 0; o < 8; ++o) {
      float wrv = Wr[o][md], wiv = Wi[o][md];
      accr0[o] = fmaf(xr0, wrv, fmaf(-xi0, wiv, accr0[o]));
      acci0[o] = fmaf(xr0, wiv, fmaf( xi0, wrv, acci0[o]));
      accr1[o] = fmaf(xr1, wrv, fmaf(-xi1, wiv, accr1[o]));
      acci1[o] = fmaf(xr1, wiv, fmaf( xi1, wrv, acci1[o]));
    }
  }
  const int mode = mode0 + md;
  const float scale = (((mode & 31) == 0) ? 1.f : 2.f) * (1.f / 65536.f);
#pragma unroll
  for (int o = 0; o < 8; ++o) {
    Cc[((size_t)(b0 + grp * 2 + 0) * 64 + (o0 + o)) * 2048 + mode] =
        make_float2(accr0[o] * scale, acci0[o] * scale);
    Cc[((size_t)(b0 + grp * 2 + 1) * 64 + (o0 + o)) * 2048 + mode] =
        make_float2(accr1[o] * scale, acci1[o] * scale);
  }
}

// ---------------- D: inverse y-DFT ----------------
// grid 1024 (b*64+o); block 256: thread = (h = hp*64 + t>>2, kx0 = (t&3)*8)
__global__ __launch_bounds__(256) void k_D(const float2* __restrict__ Cc,
                                           const float* __restrict__ twyT,
                                           float* __restrict__ Y1) {
  __shared__ float Cr[64][36], Ci[64][36];
  const int t = threadIdx.x, bo = blockIdx.x;
  const float4* Cp = (const float4*)(Cc + (size_t)bo * 2048);
#pragma unroll
  for (int j = 0; j < 4; ++j) {
    int f4 = t + 256 * j;
    float4 v = Cp[f4];
    int mode = f4 * 2;
    int mm = mode >> 5, kx = mode & 31;
    Cr[mm][kx]     = v.x; Ci[mm][kx]     = v.y;
    Cr[mm][kx + 1] = v.z; Ci[mm][kx + 1] = v.w;
  }
  __syncthreads();
  const int kx0 = (t & 3) * 8, hs = t >> 2;
  const float* cyp = twyT;
  const float* syp = twyT + 16384;
  for (int hp = 0; hp < 4; ++hp) {
    const int h = hp * 64 + hs;
    float accr[8] = {0,0,0,0,0,0,0,0};
    float accn[8] = {0,0,0,0,0,0,0,0};
#pragma unroll 2
    for (int mm = 0; mm < 64; ++mm) {
      float cy = cyp[mm * 256 + h];
      float sy = syp[mm * 256 + h];
      float4 c0 = *((const float4*)&Cr[mm][kx0]);
      float4 c1 = *((const float4*)&Cr[mm][kx0 + 4]);
      float4 d0 = *((const float4*)&Ci[mm][kx0]);
      float4 d1 = *((const float4*)&Ci[mm][kx0 + 4]);
      // Y = sum C * (cy + i sy):  re = Cr*cy - Ci*sy ; store neg-im = -(Cr*sy + Ci*cy)
#define DMAC(j, rr, ii)                                       \
      accr[j] = fmaf(rr, cy, fmaf(-(ii), sy, accr[j]));       \
      accn[j] = fmaf(-(rr), sy, fmaf(-(ii), cy, accn[j]));
      DMAC(0, c0.x, d0.x) DMAC(1, c0.y, d0.y)
      DMAC(2, c0.z, d0.z) DMAC(3, c0.w, d0.w)
      DMAC(4, c1.x, d1.x) DMAC(5, c1.y, d1.y)
      DMAC(6, c1.z, d1.z) DMAC(7, c1.w, d1.w)
#undef DMAC
    }
    float* dst = Y1 + (size_t)bo * 16384 + (size_t)h * 64 + kx0;
    *((float4*)(dst + 0))  = make_float4(accr[0], accr[1], accr[2], accr[3]);
    *((float4*)(dst + 4))  = make_float4(accr[4], accr[5], accr[6], accr[7]);
    *((float4*)(dst + 32)) = make_float4(accn[0], accn[1], accn[2], accn[3]);
    *((float4*)(dst + 36)) = make_float4(accn[4], accn[5], accn[6], accn[7]);
  }
}

// ---------------- E: inverse x-DFT + Re() ----------------
// grid 8192 row-tiles of 32; block 256: thread = (w = (t&63)*4, rows (t>>6)*8..)
__global__ __launch_bounds__(256) void k_E(const float* __restrict__ Y1,
                                           const float* __restrict__ twxT,
                                           float* __restrict__ out) {
  __shared__ float ys[32][68];
  const int t = threadIdx.x, blk = blockIdx.x;
  const float4* Yp = (const float4*)(Y1 + (size_t)blk * 2048);
#pragma unroll
  for (int j = 0; j < 2; ++j) {
    int f4 = t + 256 * j;
    int r = f4 >> 4, c4 = f4 & 15;
    *((float4*)&ys[r][c4 * 4]) = Yp[f4];
  }
  __syncthreads();
  const int wg = t & 63, rg = t >> 6;
  float acc[8][4];
#pragma unroll
  for (int r = 0; r < 8; ++r) {
    acc[r][0] = 0.f; acc[r][1] = 0.f; acc[r][2] = 0.f; acc[r][3] = 0.f;
  }
  const float4* twp = (const float4*)twxT;
#pragma unroll 2
  for (int k = 0; k < 64; ++k) {
    float4 tw = twp[k * 64 + wg];
#pragma unroll
    for (int r = 0; r < 8; ++r) {
      float yv = ys[rg * 8 + r][k];   // wave-uniform rg -> pure LDS broadcast
      acc[r][0] = fmaf(yv, tw.x, acc[r][0]);
      acc[r][1] = fmaf(yv, tw.y, acc[r][1]);
      acc[r][2] = fmaf(yv, tw.z, acc[r][2]);
      acc[r][3] = fmaf(yv, tw.w, acc[r][3]);
    }
  }
#pragma unroll
  for (int r = 0; r < 8; ++r) {
    size_t row = (size_t)blk * 32 + rg * 8 + r;
    *((float4*)(out + row * 256 + wg * 4)) =
        make_float4(acc[r][0], acc[r][1], acc[r][2], acc[r][3]);
  }
}

extern "C" void kernel_launch(void* const* d_in, const int* in_sizes, int n_in,
                              void* d_out, int out_size, void* d_ws, size_t ws_size,
                              hipStream_t stream) {
  (void)in_sizes; (void)n_in; (void)out_size; (void)ws_size;
  const float* x   = (const float*)d_in[0];
  const float* wpr = (const float*)d_in[1];
  const float* wpi = (const float*)d_in[2];
  const float* wnr = (const float*)d_in[3];
  const float* wni = (const float*)d_in[4];
  float* out = (float*)d_out;
  float* ws  = (float*)d_ws;

  // scratch inside d_out (fully overwritten by k_E at the end):
  float*  A1 = out;                                   // [1024][256][64]   = 16.78M f
  float2* X2 = (float2*)(out + 16777216);             // [1024][2048] f2   =  4.19M f
  float2* Cc = (float2*)(out + 16777216 + 4194304);   // [1024][2048] f2   =  4.19M f
  float*  Y1 = ws + T_Y1;                             // [1024][256][64]   = 16.78M f

  k_prep<<<384, 256, 0, stream>>>(ws);
  k_A<<<8192, 256, 0, stream>>>(x, ws + T_TWXA, A1);
  k_B<<<1024, 256, 0, stream>>>(A1, ws + T_TWYB, X2);
  k_C<<<512, 256, 0, stream>>>(X2, wpr, wpi, wnr, wni, Cc);
  k_D<<<1024, 256, 0, stream>>>(Cc, ws + T_TWYT, Y1);
  k_E<<<8192, 256, 0, stream>>>(Y1, ws + T_TWXT, out);
}

// Round 2
// 592.711 us; speedup vs baseline: 1.2965x; 1.2965x over previous
//
#include <hip/hip_runtime.h>
#include <math.h>

#define PI_F 3.14159265358979323846f

// Problem constants (fixed by reference):
// x:[16][64][256][256] f32, weights ×4:[64][64][32][32] f32, out:[16][64][256][256] f32
// modes: ky m=0..63 -> ky = m (m<32) else m+192 ; kx = 0..31
//
// Pipeline (separable pruned DFTs; all scratch except tables+Y1 lives in d_out):
//   A: A1[bi][h][64] = x-DFT  (cols 0..31 = Re = sum x*cos, 32..63 = Im = sum x*(-sin))
//   B: X2[bi][mode]  = y-DFT over h (conj twiddle), mode = m*32+kx, float2
//   C: Cc[b*64+o][mode] = sum_i X2 * W  (complex), * c_kx/65536
//   D: Y1[bo][h][64] = inverse-y; cols 0..31 = Re, 32..63 = -Im
//   E: out[row][w]   = dot(Y1row[64], twxT[:, w])   (cos rows | sin rows)

static constexpr int T_TWXA = 0;        // [256 w][64]   cos | -sin   (fwd x)
static constexpr int T_TWYB = 16384;    // [256 h][128]  cos[64] | sin[64] at ky(m)
static constexpr int T_TWYT = 49152;    // [2][64 m][256 h]  cos plane, sin plane
static constexpr int T_TWXT = 81920;    // [64][256]     rows 0..31 cos, 32..63 sin
static constexpr int T_Y1   = 98304;    // [1024 bo][256 h][64]

// ---------------- twiddle tables ----------------
__global__ __launch_bounds__(256) void k_prep(float* __restrict__ ws) {
  int idx = blockIdx.x * 256 + threadIdx.x;
  if (idx < 16384) {
    int w = idx >> 6, col = idx & 63, k = col & 31;
    float ang = (2.0f * PI_F / 256.0f) * (float)((k * w) & 255);
    ws[T_TWXA + idx] = (col < 32) ? cosf(ang) : -sinf(ang);
  } else if (idx < 49152) {
    int j = idx - 16384;
    int h = j >> 7, col = j & 127, m = col & 63;
    int ky = (m < 32) ? m : (m + 192);
    float ang = (2.0f * PI_F / 256.0f) * (float)((ky * h) & 255);
    ws[idx] = (col < 64) ? cosf(ang) : sinf(ang);
  } else if (idx < 81920) {
    int j = idx - 49152;
    int part = j >> 14, m = (j >> 8) & 63, h = j & 255;
    int ky = (m < 32) ? m : (m + 192);
    float ang = (2.0f * PI_F / 256.0f) * (float)((ky * h) & 255);
    ws[idx] = part ? sinf(ang) : cosf(ang);
  } else if (idx < 98304) {
    int j = idx - 81920;
    int row = j >> 8, w = j & 255, k = row & 31;
    float ang = (2.0f * PI_F / 256.0f) * (float)((k * w) & 255);
    ws[idx] = (row < 32) ? cosf(ang) : sinf(ang);
  }
}

// ---------------- A: forward x-DFT (LDS-tiled GEMM) ----------------
// C[64h × 64cols] = X[64h × 256w] · T[256w × 64cols], K-chunked by 64.
// grid 4096 = 1024 (b*64+i) × 4 h-tiles of 64 rows; block 256 = 16 cg × 16 rg.
// Per thread: 4 rows × 4 cols. Inner k: 1 ds_read_b128 (tw) + 1 ds_read_b128
// (xT, XOR-swizzled col-groups -> <=2-way bank alias on both write & read) + 16 FMA.
__global__ __launch_bounds__(256, 4) void k_A(const float* __restrict__ x,
                                              const float* __restrict__ twxA,
                                              float* __restrict__ A1) {
  __shared__ float tws[64][68];   // tws[k][col]
  __shared__ float xsT[64][68];   // xsT[k][ swz(rowgrp,k)*4 + row&3 ]
  const int t = threadIdx.x;
  const int blk = blockIdx.x;
  const int ht = blk & 3;
  const int bi = blk >> 2;
  const int cg = t & 15, rg = t >> 4;
  const float* xp = x + (size_t)bi * 65536 + (size_t)ht * 64 * 256;

  float acc[4][4];
#pragma unroll
  for (int r = 0; r < 4; ++r)
#pragma unroll
    for (int c = 0; c < 4; ++c) acc[r][c] = 0.f;

  for (int kc = 0; kc < 4; ++kc) {
    __syncthreads();
    // stage twiddle chunk: k = kc*64 + (0..63), all 64 cols
    {
      const float4* src = (const float4*)(twxA + kc * 64 * 64);
#pragma unroll
      for (int j = 0; j < 4; ++j) {
        int f4 = t + 256 * j;
        int r = f4 >> 4, c4 = f4 & 15;
        *((float4*)&tws[r][c4 * 4]) = src[f4];
      }
    }
    // stage x chunk transposed: xsT[k][row] with col-group XOR swizzle by (k>>2)&15
    {
#pragma unroll
      for (int j = 0; j < 4; ++j) {
        int f4 = t + 256 * j;
        int r = f4 >> 4;           // local h row 0..63
        int c4 = f4 & 15;          // w-group; k = c4*4+q
        float4 v = *((const float4*)(xp + (size_t)r * 256 + kc * 64 + c4 * 4));
        int g = (r >> 2) ^ c4;     // swizzled column group ((k>>2)&15 == c4)
        int col = (r & 3) + g * 4;
        xsT[c4 * 4 + 0][col] = v.x;
        xsT[c4 * 4 + 1][col] = v.y;
        xsT[c4 * 4 + 2][col] = v.z;
        xsT[c4 * 4 + 3][col] = v.w;
      }
    }
    __syncthreads();
#pragma unroll 4
    for (int k = 0; k < 64; ++k) {
      float4 tw = *((const float4*)&tws[k][cg * 4]);
      float4 xv = *((const float4*)&xsT[k][4 * (rg ^ ((k >> 2) & 15))]);
      acc[0][0] = fmaf(xv.x, tw.x, acc[0][0]);
      acc[0][1] = fmaf(xv.x, tw.y, acc[0][1]);
      acc[0][2] = fmaf(xv.x, tw.z, acc[0][2]);
      acc[0][3] = fmaf(xv.x, tw.w, acc[0][3]);
      acc[1][0] = fmaf(xv.y, tw.x, acc[1][0]);
      acc[1][1] = fmaf(xv.y, tw.y, acc[1][1]);
      acc[1][2] = fmaf(xv.y, tw.z, acc[1][2]);
      acc[1][3] = fmaf(xv.y, tw.w, acc[1][3]);
      acc[2][0] = fmaf(xv.z, tw.x, acc[2][0]);
      acc[2][1] = fmaf(xv.z, tw.y, acc[2][1]);
      acc[2][2] = fmaf(xv.z, tw.z, acc[2][2]);
      acc[2][3] = fmaf(xv.z, tw.w, acc[2][3]);
      acc[3][0] = fmaf(xv.w, tw.x, acc[3][0]);
      acc[3][1] = fmaf(xv.w, tw.y, acc[3][1]);
      acc[3][2] = fmaf(xv.w, tw.z, acc[3][2]);
      acc[3][3] = fmaf(xv.w, tw.w, acc[3][3]);
    }
  }
  const int h0 = ht * 64 + rg * 4;
  size_t base = (size_t)bi * 16384 + (size_t)h0 * 64 + cg * 4;
#pragma unroll
  for (int r = 0; r < 4; ++r) {
    *((float4*)(A1 + base + (size_t)r * 64)) =
        make_float4(acc[r][0], acc[r][1], acc[r][2], acc[r][3]);
  }
}

// ---------------- B: forward y-DFT ----------------
// grid 1024 (b*64+i); block 256: thread = (m = t>>2, kx0 = (t&3)*8)
__global__ __launch_bounds__(256) void k_B(const float* __restrict__ A1,
                                           const float* __restrict__ twyB,
                                           float2* __restrict__ X2) {
  __shared__ float as[64][68];
  const int t = threadIdx.x, bi = blockIdx.x;
  const int m = t >> 2, kx0 = (t & 3) * 8;
  float accr[8] = {0,0,0,0,0,0,0,0};
  float acci[8] = {0,0,0,0,0,0,0,0};
  const float* Ap = A1 + (size_t)bi * 16384;
  for (int hc = 0; hc < 4; ++hc) {
    __syncthreads();
    const float4* src = (const float4*)(Ap + hc * 4096);
#pragma unroll
    for (int j = 0; j < 4; ++j) {
      int f4 = t + 256 * j;
      int r = f4 >> 4, c4 = f4 & 15;
      *((float4*)&as[r][c4 * 4]) = src[f4];
    }
    __syncthreads();
    const float* ty = twyB + hc * 64 * 128;
#pragma unroll 2
    for (int h = 0; h < 64; ++h) {
      float cy = ty[h * 128 + m];
      float sy = ty[h * 128 + 64 + m];
      float4 r0 = *((const float4*)&as[h][kx0]);
      float4 r1 = *((const float4*)&as[h][kx0 + 4]);
      float4 i0 = *((const float4*)&as[h][32 + kx0]);
      float4 i1 = *((const float4*)&as[h][32 + kx0 + 4]);
      // (Ar + iAi) * (cy - i sy):  re = Ar*cy + Ai*sy ; im = Ai*cy - Ar*sy
#define CMAC_B(j, rr, ii)                                   \
      accr[j] = fmaf(rr, cy, fmaf(ii, sy, accr[j]));        \
      acci[j] = fmaf(ii, cy, fmaf(-(rr), sy, acci[j]));
      CMAC_B(0, r0.x, i0.x) CMAC_B(1, r0.y, i0.y)
      CMAC_B(2, r0.z, i0.z) CMAC_B(3, r0.w, i0.w)
      CMAC_B(4, r1.x, i1.x) CMAC_B(5, r1.y, i1.y)
      CMAC_B(6, r1.z, i1.z) CMAC_B(7, r1.w, i1.w)
#undef CMAC_B
    }
  }
  float2* dst = X2 + (size_t)bi * 2048 + m * 32 + kx0;
  float4* d4 = (float4*)dst;
  d4[0] = make_float4(accr[0], acci[0], accr[1], acci[1]);
  d4[1] = make_float4(accr[2], acci[2], accr[3], acci[3]);
  d4[2] = make_float4(accr[4], acci[4], accr[5], acci[5]);
  d4[3] = make_float4(accr[6], acci[6], accr[7], acci[7]);
}

// ---------------- C: channel mix ----------------
// grid 512 = 32 mode-chunks(64) × 2 b-tiles(8) × 8 o-tiles(8); block 256
__global__ __launch_bounds__(256) void k_C(const float2* __restrict__ X2,
                                           const float* __restrict__ wpr,
                                           const float* __restrict__ wpi,
                                           const float* __restrict__ wnr,
                                           const float* __restrict__ wni,
                                           float2* __restrict__ Cc) {
  __shared__ float Xr[8][65], Xi[8][65], Wr[8][65], Wi[8][65];
  const int t = threadIdx.x, blk = blockIdx.x;
  const int mc = blk >> 4, bt = (blk >> 3) & 1, ot = blk & 7;
  const int mode0 = mc * 64, b0 = bt * 8, o0 = ot * 8;
  const float* wr; const float* wi; int wm0;
  if (mode0 < 1024) { wr = wpr; wi = wpi; wm0 = mode0; }
  else              { wr = wnr; wi = wni; wm0 = mode0 - 1024; }
  const int md = t & 63, grp = t >> 6;    // thread: mode md, b-pair grp*2..
  float accr0[8] = {0,0,0,0,0,0,0,0};
  float acci0[8] = {0,0,0,0,0,0,0,0};
  float accr1[8] = {0,0,0,0,0,0,0,0};
  float acci1[8] = {0,0,0,0,0,0,0,0};
  for (int i = 0; i < 64; ++i) {
    __syncthreads();
#pragma unroll
    for (int j = 0; j < 2; ++j) {
      int idx = t + 256 * j;
      int r = idx >> 6, mm = idx & 63;
      float2 v = X2[((size_t)(b0 + r) * 64 + i) * 2048 + mode0 + mm];
      Xr[r][mm] = v.x; Xi[r][mm] = v.y;
      size_t wo = ((size_t)i * 64 + (o0 + r)) * 1024 + wm0 + mm;
      Wr[r][mm] = wr[wo]; Wi[r][mm] = wi[wo];
    }
    __syncthreads();
    float xr0 = Xr[grp * 2 + 0][md], xi0 = Xi[grp * 2 + 0][md];
    float xr1 = Xr[grp * 2 + 1][md], xi1 = Xi[grp * 2 + 1][md];
#pragma unroll
    for (int o = 0; o < 8; ++o) {
      float wrv = Wr[o][md], wiv = Wi[o][md];
      accr0[o] = fmaf(xr0, wrv, fmaf(-xi0, wiv, accr0[o]));
      acci0[o] = fmaf(xr0, wiv, fmaf( xi0, wrv, acci0[o]));
      accr1[o] = fmaf(xr1, wrv, fmaf(-xi1, wiv, accr1[o]));
      acci1[o] = fmaf(xr1, wiv, fmaf( xi1, wrv, acci1[o]));
    }
  }
  const int mode = mode0 + md;
  const float scale = (((mode & 31) == 0) ? 1.f : 2.f) * (1.f / 65536.f);
#pragma unroll
  for (int o = 0; o < 8; ++o) {
    Cc[((size_t)(b0 + grp * 2 + 0) * 64 + (o0 + o)) * 2048 + mode] =
        make_float2(accr0[o] * scale, acci0[o] * scale);
    Cc[((size_t)(b0 + grp * 2 + 1) * 64 + (o0 + o)) * 2048 + mode] =
        make_float2(accr1[o] * scale, acci1[o] * scale);
  }
}

// ---------------- D: inverse y-DFT ----------------
// grid 1024 (b*64+o); block 256: thread = (h = hp*64 + t>>2, kx0 = (t&3)*8)
__global__ __launch_bounds__(256) void k_D(const float2* __restrict__ Cc,
                                           const float* __restrict__ twyT,
                                           float* __restrict__ Y1) {
  __shared__ float Cr[64][36], Ci[64][36];
  const int t = threadIdx.x, bo = blockIdx.x;
  const float4* Cp = (const float4*)(Cc + (size_t)bo * 2048);
#pragma unroll
  for (int j = 0; j < 4; ++j) {
    int f4 = t + 256 * j;
    float4 v = Cp[f4];
    int mode = f4 * 2;
    int mm = mode >> 5, kx = mode & 31;
    Cr[mm][kx]     = v.x; Ci[mm][kx]     = v.y;
    Cr[mm][kx + 1] = v.z; Ci[mm][kx + 1] = v.w;
  }
  __syncthreads();
  const int kx0 = (t & 3) * 8, hs = t >> 2;
  const float* cyp = twyT;
  const float* syp = twyT + 16384;
  for (int hp = 0; hp < 4; ++hp) {
    const int h = hp * 64 + hs;
    float accr[8] = {0,0,0,0,0,0,0,0};
    float accn[8] = {0,0,0,0,0,0,0,0};
#pragma unroll 2
    for (int mm = 0; mm < 64; ++mm) {
      float cy = cyp[mm * 256 + h];
      float sy = syp[mm * 256 + h];
      float4 c0 = *((const float4*)&Cr[mm][kx0]);
      float4 c1 = *((const float4*)&Cr[mm][kx0 + 4]);
      float4 d0 = *((const float4*)&Ci[mm][kx0]);
      float4 d1 = *((const float4*)&Ci[mm][kx0 + 4]);
      // Y = sum C * (cy + i sy):  re = Cr*cy - Ci*sy ; store neg-im = -(Cr*sy + Ci*cy)
#define DMAC(j, rr, ii)                                       \
      accr[j] = fmaf(rr, cy, fmaf(-(ii), sy, accr[j]));       \
      accn[j] = fmaf(-(rr), sy, fmaf(-(ii), cy, accn[j]));
      DMAC(0, c0.x, d0.x) DMAC(1, c0.y, d0.y)
      DMAC(2, c0.z, d0.z) DMAC(3, c0.w, d0.w)
      DMAC(4, c1.x, d1.x) DMAC(5, c1.y, d1.y)
      DMAC(6, c1.z, d1.z) DMAC(7, c1.w, d1.w)
#undef DMAC
    }
    float* dst = Y1 + (size_t)bo * 16384 + (size_t)h * 64 + kx0;
    *((float4*)(dst + 0))  = make_float4(accr[0], accr[1], accr[2], accr[3]);
    *((float4*)(dst + 4))  = make_float4(accr[4], accr[5], accr[6], accr[7]);
    *((float4*)(dst + 32)) = make_float4(accn[0], accn[1], accn[2], accn[3]);
    *((float4*)(dst + 36)) = make_float4(accn[4], accn[5], accn[6], accn[7]);
  }
}

// ---------------- E: inverse x-DFT + Re() ----------------
// grid 8192 row-tiles of 32; block 256: thread = (w = (t&63)*4, rows (t>>6)*8..)
__global__ __launch_bounds__(256) void k_E(const float* __restrict__ Y1,
                                           const float* __restrict__ twxT,
                                           float* __restrict__ out) {
  __shared__ float ys[32][68];
  const int t = threadIdx.x, blk = blockIdx.x;
  const float4* Yp = (const float4*)(Y1 + (size_t)blk * 2048);
#pragma unroll
  for (int j = 0; j < 2; ++j) {
    int f4 = t + 256 * j;
    int r = f4 >> 4, c4 = f4 & 15;
    *((float4*)&ys[r][c4 * 4]) = Yp[f4];
  }
  __syncthreads();
  const int wg = t & 63, rg = t >> 6;
  float acc[8][4];
#pragma unroll
  for (int r = 0; r < 8; ++r) {
    acc[r][0] = 0.f; acc[r][1] = 0.f; acc[r][2] = 0.f; acc[r][3] = 0.f;
  }
  const float4* twp = (const float4*)twxT;
#pragma unroll 2
  for (int k = 0; k < 64; ++k) {
    float4 tw = twp[k * 64 + wg];
#pragma unroll
    for (int r = 0; r < 8; ++r) {
      float yv = ys[rg * 8 + r][k];   // wave-uniform rg -> pure LDS broadcast
      acc[r][0] = fmaf(yv, tw.x, acc[r][0]);
      acc[r][1] = fmaf(yv, tw.y, acc[r][1]);
      acc[r][2] = fmaf(yv, tw.z, acc[r][2]);
      acc[r][3] = fmaf(yv, tw.w, acc[r][3]);
    }
  }
#pragma unroll
  for (int r = 0; r < 8; ++r) {
    size_t row = (size_t)blk * 32 + rg * 8 + r;
    *((float4*)(out + row * 256 + wg * 4)) =
        make_float4(acc[r][0], acc[r][1], acc[r][2], acc[r][3]);
  }
}

extern "C" void kernel_launch(void* const* d_in, const int* in_sizes, int n_in,
                              void* d_out, int out_size, void* d_ws, size_t ws_size,
                              hipStream_t stream) {
  (void)in_sizes; (void)n_in; (void)out_size; (void)ws_size;
  const float* x   = (const float*)d_in[0];
  const float* wpr = (const float*)d_in[1];
  const float* wpi = (const float*)d_in[2];
  const float* wnr = (const float*)d_in[3];
  const float* wni = (const float*)d_in[4];
  float* out = (float*)d_out;
  float* ws  = (float*)d_ws;

  // scratch inside d_out (fully overwritten by k_E at the end):
  float*  A1 = out;                                   // [1024][256][64]   = 16.78M f
  float2* X2 = (float2*)(out + 16777216);             // [1024][2048] f2   =  4.19M f
  float2* Cc = (float2*)(out + 16777216 + 4194304);   // [1024][2048] f2   =  4.19M f
  float*  Y1 = ws + T_Y1;                             // [1024][256][64]   = 16.78M f

  k_prep<<<384, 256, 0, stream>>>(ws);
  k_A<<<4096, 256, 0, stream>>>(x, ws + T_TWXA, A1);
  k_B<<<1024, 256, 0, stream>>>(A1, ws + T_TWYB, X2);
  k_C<<<512, 256, 0, stream>>>(X2, wpr, wpi, wnr, wni, Cc);
  k_D<<<1024, 256, 0, stream>>>(Cc, ws + T_TWYT, Y1);
  k_E<<<8192, 256, 0, stream>>>(Y1, ws + T_TWXT, out);
}

// Round 3
// 587.036 us; speedup vs baseline: 1.3091x; 1.0097x over previous
//
#include <hip/hip_runtime.h>
#include <math.h>

#define PI_F 3.14159265358979323846f

// Problem constants (fixed by reference):
// x:[16][64][256][256] f32, weights ×4:[64][64][32][32] f32, out:[16][64][256][256] f32
// modes: ky m=0..63 -> ky = m (m<32) else m+192 ; kx = 0..31
//
// Pipeline (separable pruned DFTs; all scratch except tables+Y1 lives in d_out):
//   A: A1[bi][h][64] = x-DFT  (cols 0..31 = Re = sum x*cos, 32..63 = Im = sum x*(-sin))
//   B: X2[bi][mode]  = y-DFT over h (conj twiddle), mode = m*32+kx, float2
//   C: Cc[b*64+o][mode] = sum_i X2 * W  (complex), * c_kx/65536
//   D: Y1[bo][h][64] = inverse-y; cols 0..31 = Re, 32..63 = -Im
//   E: out[row][w]   = dot(Y1row[64], twxT[:, w])   (cos rows | sin rows)

static constexpr int T_TWXA = 0;        // [256 w][64]   cos | -sin   (fwd x)
static constexpr int T_TWYB = 16384;    // [256 h][128]  cos[64] | sin[64] at ky(m)
static constexpr int T_TWYT = 49152;    // [2][64 m][256 h]  cos plane, sin plane
static constexpr int T_TWXT = 81920;    // [64][256]     rows 0..31 cos, 32..63 sin
static constexpr int T_Y1   = 98304;    // [1024 bo][256 h][64]

// ---------------- twiddle tables ----------------
__global__ __launch_bounds__(256) void k_prep(float* __restrict__ ws) {
  int idx = blockIdx.x * 256 + threadIdx.x;
  if (idx < 16384) {
    int w = idx >> 6, col = idx & 63, k = col & 31;
    float ang = (2.0f * PI_F / 256.0f) * (float)((k * w) & 255);
    ws[T_TWXA + idx] = (col < 32) ? cosf(ang) : -sinf(ang);
  } else if (idx < 49152) {
    int j = idx - 16384;
    int h = j >> 7, col = j & 127, m = col & 63;
    int ky = (m < 32) ? m : (m + 192);
    float ang = (2.0f * PI_F / 256.0f) * (float)((ky * h) & 255);
    ws[idx] = (col < 64) ? cosf(ang) : sinf(ang);
  } else if (idx < 81920) {
    int j = idx - 49152;
    int part = j >> 14, m = (j >> 8) & 63, h = j & 255;
    int ky = (m < 32) ? m : (m + 192);
    float ang = (2.0f * PI_F / 256.0f) * (float)((ky * h) & 255);
    ws[idx] = part ? sinf(ang) : cosf(ang);
  } else if (idx < 98304) {
    int j = idx - 81920;
    int row = j >> 8, w = j & 255, k = row & 31;
    float ang = (2.0f * PI_F / 256.0f) * (float)((k * w) & 255);
    ws[idx] = (row < 32) ? cosf(ang) : sinf(ang);
  }
}

// ---------------- A: forward x-DFT (LDS-tiled GEMM) ----------------
// C[64h × 64cols] = X[64h × 256w] · T[256w × 64cols], K-chunked by 64.
// grid 4096 = 1024 (b*64+i) × 4 h-tiles of 64 rows; block 256 = 16 cg × 16 rg.
__global__ __launch_bounds__(256, 4) void k_A(const float* __restrict__ x,
                                              const float* __restrict__ twxA,
                                              float* __restrict__ A1) {
  __shared__ float tws[64][68];   // tws[k][col]
  __shared__ float xsT[64][68];   // xsT[k][ swz(rowgrp,k)*4 + row&3 ]
  const int t = threadIdx.x;
  const int blk = blockIdx.x;
  const int ht = blk & 3;
  const int bi = blk >> 2;
  const int cg = t & 15, rg = t >> 4;
  const float* xp = x + (size_t)bi * 65536 + (size_t)ht * 64 * 256;

  float acc[4][4];
#pragma unroll
  for (int r = 0; r < 4; ++r)
#pragma unroll
    for (int c = 0; c < 4; ++c) acc[r][c] = 0.f;

  for (int kc = 0; kc < 4; ++kc) {
    __syncthreads();
    // stage twiddle chunk: k = kc*64 + (0..63), all 64 cols
    {
      const float4* src = (const float4*)(twxA + kc * 64 * 64);
#pragma unroll
      for (int j = 0; j < 4; ++j) {
        int f4 = t + 256 * j;
        int r = f4 >> 4, c4 = f4 & 15;
        *((float4*)&tws[r][c4 * 4]) = src[f4];
      }
    }
    // stage x chunk transposed: xsT[k][row] with col-group XOR swizzle by (k>>2)&15
    {
#pragma unroll
      for (int j = 0; j < 4; ++j) {
        int f4 = t + 256 * j;
        int r = f4 >> 4;           // local h row 0..63
        int c4 = f4 & 15;          // w-group; k = c4*4+q
        float4 v = *((const float4*)(xp + (size_t)r * 256 + kc * 64 + c4 * 4));
        int g = (r >> 2) ^ c4;     // swizzled column group ((k>>2)&15 == c4)
        int col = (r & 3) + g * 4;
        xsT[c4 * 4 + 0][col] = v.x;
        xsT[c4 * 4 + 1][col] = v.y;
        xsT[c4 * 4 + 2][col] = v.z;
        xsT[c4 * 4 + 3][col] = v.w;
      }
    }
    __syncthreads();
#pragma unroll 4
    for (int k = 0; k < 64; ++k) {
      float4 tw = *((const float4*)&tws[k][cg * 4]);
      float4 xv = *((const float4*)&xsT[k][4 * (rg ^ ((k >> 2) & 15))]);
      acc[0][0] = fmaf(xv.x, tw.x, acc[0][0]);
      acc[0][1] = fmaf(xv.x, tw.y, acc[0][1]);
      acc[0][2] = fmaf(xv.x, tw.z, acc[0][2]);
      acc[0][3] = fmaf(xv.x, tw.w, acc[0][3]);
      acc[1][0] = fmaf(xv.y, tw.x, acc[1][0]);
      acc[1][1] = fmaf(xv.y, tw.y, acc[1][1]);
      acc[1][2] = fmaf(xv.y, tw.z, acc[1][2]);
      acc[1][3] = fmaf(xv.y, tw.w, acc[1][3]);
      acc[2][0] = fmaf(xv.z, tw.x, acc[2][0]);
      acc[2][1] = fmaf(xv.z, tw.y, acc[2][1]);
      acc[2][2] = fmaf(xv.z, tw.z, acc[2][2]);
      acc[2][3] = fmaf(xv.z, tw.w, acc[2][3]);
      acc[3][0] = fmaf(xv.w, tw.x, acc[3][0]);
      acc[3][1] = fmaf(xv.w, tw.y, acc[3][1]);
      acc[3][2] = fmaf(xv.w, tw.z, acc[3][2]);
      acc[3][3] = fmaf(xv.w, tw.w, acc[3][3]);
    }
  }
  const int h0 = ht * 64 + rg * 4;
  size_t base = (size_t)bi * 16384 + (size_t)h0 * 64 + cg * 4;
#pragma unroll
  for (int r = 0; r < 4; ++r) {
    *((float4*)(A1 + base + (size_t)r * 64)) =
        make_float4(acc[r][0], acc[r][1], acc[r][2], acc[r][3]);
  }
}

// ---------------- B: forward y-DFT ----------------
// grid 1024 (b*64+i); block 256: thread = (m = t>>2, kx0 = (t&3)*8)
__global__ __launch_bounds__(256) void k_B(const float* __restrict__ A1,
                                           const float* __restrict__ twyB,
                                           float2* __restrict__ X2) {
  __shared__ float as[64][68];
  const int t = threadIdx.x, bi = blockIdx.x;
  const int m = t >> 2, kx0 = (t & 3) * 8;
  float accr[8] = {0,0,0,0,0,0,0,0};
  float acci[8] = {0,0,0,0,0,0,0,0};
  const float* Ap = A1 + (size_t)bi * 16384;
  for (int hc = 0; hc < 4; ++hc) {
    __syncthreads();
    const float4* src = (const float4*)(Ap + hc * 4096);
#pragma unroll
    for (int j = 0; j < 4; ++j) {
      int f4 = t + 256 * j;
      int r = f4 >> 4, c4 = f4 & 15;
      *((float4*)&as[r][c4 * 4]) = src[f4];
    }
    __syncthreads();
    const float* ty = twyB + hc * 64 * 128;
#pragma unroll 2
    for (int h = 0; h < 64; ++h) {
      float cy = ty[h * 128 + m];
      float sy = ty[h * 128 + 64 + m];
      float4 r0 = *((const float4*)&as[h][kx0]);
      float4 r1 = *((const float4*)&as[h][kx0 + 4]);
      float4 i0 = *((const float4*)&as[h][32 + kx0]);
      float4 i1 = *((const float4*)&as[h][32 + kx0 + 4]);
      // (Ar + iAi) * (cy - i sy):  re = Ar*cy + Ai*sy ; im = Ai*cy - Ar*sy
#define CMAC_B(j, rr, ii)                                   \
      accr[j] = fmaf(rr, cy, fmaf(ii, sy, accr[j]));        \
      acci[j] = fmaf(ii, cy, fmaf(-(rr), sy, acci[j]));
      CMAC_B(0, r0.x, i0.x) CMAC_B(1, r0.y, i0.y)
      CMAC_B(2, r0.z, i0.z) CMAC_B(3, r0.w, i0.w)
      CMAC_B(4, r1.x, i1.x) CMAC_B(5, r1.y, i1.y)
      CMAC_B(6, r1.z, i1.z) CMAC_B(7, r1.w, i1.w)
#undef CMAC_B
    }
  }
  float2* dst = X2 + (size_t)bi * 2048 + m * 32 + kx0;
  float4* d4 = (float4*)dst;
  d4[0] = make_float4(accr[0], acci[0], accr[1], acci[1]);
  d4[1] = make_float4(accr[2], acci[2], accr[3], acci[3]);
  d4[2] = make_float4(accr[4], acci[4], accr[5], acci[5]);
  d4[3] = make_float4(accr[6], acci[6], accr[7], acci[7]);
}

// ---------------- C: channel mix (one block per mode) ----------------
// grid 2048 (mode); block 256. Stage W[64i][64o] (32 KB) + X[16b][64i] (8 KB)
// once, one barrier, then thread (o = t&63, bg = t>>6) computes 4 b-outputs.
// bg is wave-uniform -> X reads are pure LDS broadcasts (no padding needed);
// Xs[b][i] layout makes staging writes conflict-free.
__global__ __launch_bounds__(256, 4) void k_C(const float2* __restrict__ X2,
                                              const float* __restrict__ wpr,
                                              const float* __restrict__ wpi,
                                              const float* __restrict__ wnr,
                                              const float* __restrict__ wni,
                                              float2* __restrict__ Cc) {
  __shared__ float2 Xs[16][64];    // [b][i]
  __shared__ float2 Wsh[64][64];   // [i][o]
  const int t = threadIdx.x;
  const int mode = blockIdx.x;
  const float* wr; const float* wi; int wm;
  if (mode < 1024) { wr = wpr; wi = wpi; wm = mode; }
  else             { wr = wnr; wi = wni; wm = mode - 1024; }

  // issue all global loads early (latency overlapped across 4 blocks/CU)
  float2 xv[4];
#pragma unroll
  for (int j = 0; j < 4; ++j) {
    int bi = t + 256 * j;                        // b = bi>>6, i = bi&63
    xv[j] = X2[(size_t)bi * 2048 + mode];
  }
  float wre[16], wim[16];
#pragma unroll
  for (int k = 0; k < 16; ++k) {
    int io = t + 256 * k;                        // i = io>>6, o = io&63
    size_t a = (size_t)io * 1024 + wm;
    wre[k] = wr[a];
    wim[k] = wi[a];
  }
#pragma unroll
  for (int j = 0; j < 4; ++j) {
    int bi = t + 256 * j;
    Xs[bi >> 6][bi & 63] = xv[j];                // lanes: i consecutive -> conflict-free
  }
#pragma unroll
  for (int k = 0; k < 16; ++k) {
    int io = t + 256 * k;
    Wsh[io >> 6][io & 63] = make_float2(wre[k], wim[k]);
  }
  __syncthreads();

  const int o = t & 63, bg = t >> 6;             // bg wave-uniform
  float accr[4] = {0.f, 0.f, 0.f, 0.f};
  float acci[4] = {0.f, 0.f, 0.f, 0.f};
#pragma unroll 4
  for (int i = 0; i < 64; ++i) {
    float2 w = Wsh[i][o];
    float2 x0 = Xs[bg * 4 + 0][i];
    float2 x1 = Xs[bg * 4 + 1][i];
    float2 x2 = Xs[bg * 4 + 2][i];
    float2 x3 = Xs[bg * 4 + 3][i];
    accr[0] = fmaf(x0.x, w.x, fmaf(-x0.y, w.y, accr[0]));
    acci[0] = fmaf(x0.x, w.y, fmaf( x0.y, w.x, acci[0]));
    accr[1] = fmaf(x1.x, w.x, fmaf(-x1.y, w.y, accr[1]));
    acci[1] = fmaf(x1.x, w.y, fmaf( x1.y, w.x, acci[1]));
    accr[2] = fmaf(x2.x, w.x, fmaf(-x2.y, w.y, accr[2]));
    acci[2] = fmaf(x2.x, w.y, fmaf( x2.y, w.x, acci[2]));
    accr[3] = fmaf(x3.x, w.x, fmaf(-x3.y, w.y, accr[3]));
    acci[3] = fmaf(x3.x, w.y, fmaf( x3.y, w.x, acci[3]));
  }

  const float scale = (((mode & 31) == 0) ? 1.f : 2.f) * (1.f / 65536.f);
#pragma unroll
  for (int j = 0; j < 4; ++j) {
    int b = bg * 4 + j;
    Cc[(size_t)(b * 64 + o) * 2048 + mode] =
        make_float2(accr[j] * scale, acci[j] * scale);
  }
}

// ---------------- D: inverse y-DFT ----------------
// grid 1024 (b*64+o); block 256: thread = (h = hp*64 + t>>2, kx0 = (t&3)*8)
__global__ __launch_bounds__(256) void k_D(const float2* __restrict__ Cc,
                                           const float* __restrict__ twyT,
                                           float* __restrict__ Y1) {
  __shared__ float Cr[64][36], Ci[64][36];
  const int t = threadIdx.x, bo = blockIdx.x;
  const float4* Cp = (const float4*)(Cc + (size_t)bo * 2048);
#pragma unroll
  for (int j = 0; j < 4; ++j) {
    int f4 = t + 256 * j;
    float4 v = Cp[f4];
    int mode = f4 * 2;
    int mm = mode >> 5, kx = mode & 31;
    Cr[mm][kx]     = v.x; Ci[mm][kx]     = v.y;
    Cr[mm][kx + 1] = v.z; Ci[mm][kx + 1] = v.w;
  }
  __syncthreads();
  const int kx0 = (t & 3) * 8, hs = t >> 2;
  const float* cyp = twyT;
  const float* syp = twyT + 16384;
  for (int hp = 0; hp < 4; ++hp) {
    const int h = hp * 64 + hs;
    float accr[8] = {0,0,0,0,0,0,0,0};
    float accn[8] = {0,0,0,0,0,0,0,0};
#pragma unroll 2
    for (int mm = 0; mm < 64; ++mm) {
      float cy = cyp[mm * 256 + h];
      float sy = syp[mm * 256 + h];
      float4 c0 = *((const float4*)&Cr[mm][kx0]);
      float4 c1 = *((const float4*)&Cr[mm][kx0 + 4]);
      float4 d0 = *((const float4*)&Ci[mm][kx0]);
      float4 d1 = *((const float4*)&Ci[mm][kx0 + 4]);
      // Y = sum C * (cy + i sy):  re = Cr*cy - Ci*sy ; store neg-im = -(Cr*sy + Ci*cy)
#define DMAC(j, rr, ii)                                       \
      accr[j] = fmaf(rr, cy, fmaf(-(ii), sy, accr[j]));       \
      accn[j] = fmaf(-(rr), sy, fmaf(-(ii), cy, accn[j]));
      DMAC(0, c0.x, d0.x) DMAC(1, c0.y, d0.y)
      DMAC(2, c0.z, d0.z) DMAC(3, c0.w, d0.w)
      DMAC(4, c1.x, d1.x) DMAC(5, c1.y, d1.y)
      DMAC(6, c1.z, d1.z) DMAC(7, c1.w, d1.w)
#undef DMAC
    }
    float* dst = Y1 + (size_t)bo * 16384 + (size_t)h * 64 + kx0;
    *((float4*)(dst + 0))  = make_float4(accr[0], accr[1], accr[2], accr[3]);
    *((float4*)(dst + 4))  = make_float4(accr[4], accr[5], accr[6], accr[7]);
    *((float4*)(dst + 32)) = make_float4(accn[0], accn[1], accn[2], accn[3]);
    *((float4*)(dst + 36)) = make_float4(accn[4], accn[5], accn[6], accn[7]);
  }
}

// ---------------- E: inverse x-DFT + Re() ----------------
// grid 8192 row-tiles of 32; block 256: thread = (w = (t&63)*4, rows (t>>6)*8..)
__global__ __launch_bounds__(256) void k_E(const float* __restrict__ Y1,
                                           const float* __restrict__ twxT,
                                           float* __restrict__ out) {
  __shared__ float ys[32][68];
  const int t = threadIdx.x, blk = blockIdx.x;
  const float4* Yp = (const float4*)(Y1 + (size_t)blk * 2048);
#pragma unroll
  for (int j = 0; j < 2; ++j) {
    int f4 = t + 256 * j;
    int r = f4 >> 4, c4 = f4 & 15;
    *((float4*)&ys[r][c4 * 4]) = Yp[f4];
  }
  __syncthreads();
  const int wg = t & 63, rg = t >> 6;
  float acc[8][4];
#pragma unroll
  for (int r = 0; r < 8; ++r) {
    acc[r][0] = 0.f; acc[r][1] = 0.f; acc[r][2] = 0.f; acc[r][3] = 0.f;
  }
  const float4* twp = (const float4*)twxT;
#pragma unroll 2
  for (int k = 0; k < 64; ++k) {
    float4 tw = twp[k * 64 + wg];
#pragma unroll
    for (int r = 0; r < 8; ++r) {
      float yv = ys[rg * 8 + r][k];   // wave-uniform rg -> pure LDS broadcast
      acc[r][0] = fmaf(yv, tw.x, acc[r][0]);
      acc[r][1] = fmaf(yv, tw.y, acc[r][1]);
      acc[r][2] = fmaf(yv, tw.z, acc[r][2]);
      acc[r][3] = fmaf(yv, tw.w, acc[r][3]);
    }
  }
#pragma unroll
  for (int r = 0; r < 8; ++r) {
    size_t row = (size_t)blk * 32 + rg * 8 + r;
    *((float4*)(out + row * 256 + wg * 4)) =
        make_float4(acc[r][0], acc[r][1], acc[r][2], acc[r][3]);
  }
}

extern "C" void kernel_launch(void* const* d_in, const int* in_sizes, int n_in,
                              void* d_out, int out_size, void* d_ws, size_t ws_size,
                              hipStream_t stream) {
  (void)in_sizes; (void)n_in; (void)out_size; (void)ws_size;
  const float* x   = (const float*)d_in[0];
  const float* wpr = (const float*)d_in[1];
  const float* wpi = (const float*)d_in[2];
  const float* wnr = (const float*)d_in[3];
  const float* wni = (const float*)d_in[4];
  float* out = (float*)d_out;
  float* ws  = (float*)d_ws;

  // scratch inside d_out (fully overwritten by k_E at the end):
  float*  A1 = out;                                   // [1024][256][64]   = 16.78M f
  float2* X2 = (float2*)(out + 16777216);             // [1024][2048] f2   =  4.19M f
  float2* Cc = (float2*)(out + 16777216 + 4194304);   // [1024][2048] f2   =  4.19M f
  float*  Y1 = ws + T_Y1;                             // [1024][256][64]   = 16.78M f

  k_prep<<<384, 256, 0, stream>>>(ws);
  k_A<<<4096, 256, 0, stream>>>(x, ws + T_TWXA, A1);
  k_B<<<1024, 256, 0, stream>>>(A1, ws + T_TWYB, X2);
  k_C<<<2048, 256, 0, stream>>>(X2, wpr, wpi, wnr, wni, Cc);
  k_D<<<1024, 256, 0, stream>>>(Cc, ws + T_TWYT, Y1);
  k_E<<<8192, 256, 0, stream>>>(Y1, ws + T_TWXT, out);
}

// Round 4
// 552.194 us; speedup vs baseline: 1.3917x; 1.0631x over previous
//
#include <hip/hip_runtime.h>
#include <math.h>

#define PI_F 3.14159265358979323846f

// Problem constants (fixed by reference):
// x:[16][64][256][256] f32, weights ×4:[64][64][32][32] f32, out:[16][64][256][256] f32
// modes: ky m=0..63 -> ky = m (m<32) else m+192 ; kx = 0..31
//
// Pipeline (separable pruned DFTs; all scratch except tables+Y1 lives in d_out):
//   A: A1[bi][h][64] = x-DFT  (cols 0..31 = Re = sum x*cos, 32..63 = Im = sum x*(-sin))
//   B: X2[bi][mode]  = y-DFT over h (conj twiddle), mode = m*32+kx, float2
//   C: Cc[b*64+o][mode] = sum_i X2 * W  (complex), * c_kx/65536
//   D: Y1[bo][h][64] = inverse-y; cols 0..31 = Re, 32..63 = -Im
//   E: out[row][w]   = dot(Y1row[64], twxT[:, w])   (cos rows | sin rows)

static constexpr int T_TWXA = 0;        // [256 w][64]   cos | -sin   (fwd x)
static constexpr int T_TWYB = 16384;    // [256 h][128]  cos[64] | sin[64] at ky(m)
static constexpr int T_TWYT = 49152;    // [2][64 m][256 h]  cos plane, sin plane
static constexpr int T_TWXT = 81920;    // [64][256]     rows 0..31 cos, 32..63 sin
static constexpr int T_Y1   = 98304;    // [1024 bo][256 h][64]

// ---------------- twiddle tables ----------------
__global__ __launch_bounds__(256) void k_prep(float* __restrict__ ws) {
  int idx = blockIdx.x * 256 + threadIdx.x;
  if (idx < 16384) {
    int w = idx >> 6, col = idx & 63, k = col & 31;
    float ang = (2.0f * PI_F / 256.0f) * (float)((k * w) & 255);
    ws[T_TWXA + idx] = (col < 32) ? cosf(ang) : -sinf(ang);
  } else if (idx < 49152) {
    int j = idx - 16384;
    int h = j >> 7, col = j & 127, m = col & 63;
    int ky = (m < 32) ? m : (m + 192);
    float ang = (2.0f * PI_F / 256.0f) * (float)((ky * h) & 255);
    ws[idx] = (col < 64) ? cosf(ang) : sinf(ang);
  } else if (idx < 81920) {
    int j = idx - 49152;
    int part = j >> 14, m = (j >> 8) & 63, h = j & 255;
    int ky = (m < 32) ? m : (m + 192);
    float ang = (2.0f * PI_F / 256.0f) * (float)((ky * h) & 255);
    ws[idx] = part ? sinf(ang) : cosf(ang);
  } else if (idx < 98304) {
    int j = idx - 81920;
    int row = j >> 8, w = j & 255, k = row & 31;
    float ang = (2.0f * PI_F / 256.0f) * (float)((k * w) & 255);
    ws[idx] = (row < 32) ? cosf(ang) : sinf(ang);
  }
}

// ---------------- A: forward x-DFT (LDS-tiled GEMM) ----------------
// C[64h × 64cols] = X[64h × 256w] · T[256w × 64cols], K-chunked by 64.
// grid 4096 = 1024 (b*64+i) × 4 h-tiles of 64 rows; block 256 = 16 cg × 16 rg.
__global__ __launch_bounds__(256, 4) void k_A(const float* __restrict__ x,
                                              const float* __restrict__ twxA,
                                              float* __restrict__ A1) {
  __shared__ float tws[64][68];   // tws[k][col]
  __shared__ float xsT[64][68];   // xsT[k][ swz(rowgrp,k)*4 + row&3 ]
  const int t = threadIdx.x;
  const int blk = blockIdx.x;
  const int ht = blk & 3;
  const int bi = blk >> 2;
  const int cg = t & 15, rg = t >> 4;
  const float* xp = x + (size_t)bi * 65536 + (size_t)ht * 64 * 256;

  float acc[4][4];
#pragma unroll
  for (int r = 0; r < 4; ++r)
#pragma unroll
    for (int c = 0; c < 4; ++c) acc[r][c] = 0.f;

  for (int kc = 0; kc < 4; ++kc) {
    __syncthreads();
    // stage twiddle chunk: k = kc*64 + (0..63), all 64 cols
    {
      const float4* src = (const float4*)(twxA + kc * 64 * 64);
#pragma unroll
      for (int j = 0; j < 4; ++j) {
        int f4 = t + 256 * j;
        int r = f4 >> 4, c4 = f4 & 15;
        *((float4*)&tws[r][c4 * 4]) = src[f4];
      }
    }
    // stage x chunk transposed: xsT[k][row] with col-group XOR swizzle by (k>>2)&15
    {
#pragma unroll
      for (int j = 0; j < 4; ++j) {
        int f4 = t + 256 * j;
        int r = f4 >> 4;           // local h row 0..63
        int c4 = f4 & 15;          // w-group; k = c4*4+q
        float4 v = *((const float4*)(xp + (size_t)r * 256 + kc * 64 + c4 * 4));
        int g = (r >> 2) ^ c4;     // swizzled column group ((k>>2)&15 == c4)
        int col = (r & 3) + g * 4;
        xsT[c4 * 4 + 0][col] = v.x;
        xsT[c4 * 4 + 1][col] = v.y;
        xsT[c4 * 4 + 2][col] = v.z;
        xsT[c4 * 4 + 3][col] = v.w;
      }
    }
    __syncthreads();
#pragma unroll 4
    for (int k = 0; k < 64; ++k) {
      float4 tw = *((const float4*)&tws[k][cg * 4]);
      float4 xv = *((const float4*)&xsT[k][4 * (rg ^ ((k >> 2) & 15))]);
      acc[0][0] = fmaf(xv.x, tw.x, acc[0][0]);
      acc[0][1] = fmaf(xv.x, tw.y, acc[0][1]);
      acc[0][2] = fmaf(xv.x, tw.z, acc[0][2]);
      acc[0][3] = fmaf(xv.x, tw.w, acc[0][3]);
      acc[1][0] = fmaf(xv.y, tw.x, acc[1][0]);
      acc[1][1] = fmaf(xv.y, tw.y, acc[1][1]);
      acc[1][2] = fmaf(xv.y, tw.z, acc[1][2]);
      acc[1][3] = fmaf(xv.y, tw.w, acc[1][3]);
      acc[2][0] = fmaf(xv.z, tw.x, acc[2][0]);
      acc[2][1] = fmaf(xv.z, tw.y, acc[2][1]);
      acc[2][2] = fmaf(xv.z, tw.z, acc[2][2]);
      acc[2][3] = fmaf(xv.z, tw.w, acc[2][3]);
      acc[3][0] = fmaf(xv.w, tw.x, acc[3][0]);
      acc[3][1] = fmaf(xv.w, tw.y, acc[3][1]);
      acc[3][2] = fmaf(xv.w, tw.z, acc[3][2]);
      acc[3][3] = fmaf(xv.w, tw.w, acc[3][3]);
    }
  }
  const int h0 = ht * 64 + rg * 4;
  size_t base = (size_t)bi * 16384 + (size_t)h0 * 64 + cg * 4;
#pragma unroll
  for (int r = 0; r < 4; ++r) {
    *((float4*)(A1 + base + (size_t)r * 64)) =
        make_float4(acc[r][0], acc[r][1], acc[r][2], acc[r][3]);
  }
}

// ---------------- B: forward y-DFT ----------------
// grid 1024 (b*64+i); block 256: thread = (m = t>>2, kx0 = (t&3)*8)
__global__ __launch_bounds__(256) void k_B(const float* __restrict__ A1,
                                           const float* __restrict__ twyB,
                                           float2* __restrict__ X2) {
  __shared__ float as[64][68];
  const int t = threadIdx.x, bi = blockIdx.x;
  const int m = t >> 2, kx0 = (t & 3) * 8;
  float accr[8] = {0,0,0,0,0,0,0,0};
  float acci[8] = {0,0,0,0,0,0,0,0};
  const float* Ap = A1 + (size_t)bi * 16384;
  for (int hc = 0; hc < 4; ++hc) {
    __syncthreads();
    const float4* src = (const float4*)(Ap + hc * 4096);
#pragma unroll
    for (int j = 0; j < 4; ++j) {
      int f4 = t + 256 * j;
      int r = f4 >> 4, c4 = f4 & 15;
      *((float4*)&as[r][c4 * 4]) = src[f4];
    }
    __syncthreads();
    const float* ty = twyB + hc * 64 * 128;
#pragma unroll 2
    for (int h = 0; h < 64; ++h) {
      float cy = ty[h * 128 + m];
      float sy = ty[h * 128 + 64 + m];
      float4 r0 = *((const float4*)&as[h][kx0]);
      float4 r1 = *((const float4*)&as[h][kx0 + 4]);
      float4 i0 = *((const float4*)&as[h][32 + kx0]);
      float4 i1 = *((const float4*)&as[h][32 + kx0 + 4]);
      // (Ar + iAi) * (cy - i sy):  re = Ar*cy + Ai*sy ; im = Ai*cy - Ar*sy
#define CMAC_B(j, rr, ii)                                   \
      accr[j] = fmaf(rr, cy, fmaf(ii, sy, accr[j]));        \
      acci[j] = fmaf(ii, cy, fmaf(-(rr), sy, acci[j]));
      CMAC_B(0, r0.x, i0.x) CMAC_B(1, r0.y, i0.y)
      CMAC_B(2, r0.z, i0.z) CMAC_B(3, r0.w, i0.w)
      CMAC_B(4, r1.x, i1.x) CMAC_B(5, r1.y, i1.y)
      CMAC_B(6, r1.z, i1.z) CMAC_B(7, r1.w, i1.w)
#undef CMAC_B
    }
  }
  float2* dst = X2 + (size_t)bi * 2048 + m * 32 + kx0;
  float4* d4 = (float4*)dst;
  d4[0] = make_float4(accr[0], acci[0], accr[1], acci[1]);
  d4[1] = make_float4(accr[2], acci[2], accr[3], acci[3]);
  d4[2] = make_float4(accr[4], acci[4], accr[5], acci[5]);
  d4[3] = make_float4(accr[6], acci[6], accr[7], acci[7]);
}

// ---------------- C: channel mix (one block per mode, XCD-chunked) ----------------
// grid 2048; mode = (bid&7)*256 + (bid>>3): each XCD owns a contiguous 256-mode
// range, so the 16 mode-blocks sharing each 64B weight line (and 8 sharing each
// X2 line) hit the same per-XCD L2 -> HBM reads W/X2 once.
__global__ __launch_bounds__(256, 4) void k_C(const float2* __restrict__ X2,
                                              const float* __restrict__ wpr,
                                              const float* __restrict__ wpi,
                                              const float* __restrict__ wnr,
                                              const float* __restrict__ wni,
                                              float2* __restrict__ Cc) {
  __shared__ float2 Xs[16][64];    // [b][i]
  __shared__ float2 Wsh[64][64];   // [i][o]
  const int t = threadIdx.x;
  const int bid = blockIdx.x;
  const int mode = (bid & 7) * 256 + (bid >> 3);   // bijective XCD-chunked map
  const float* wr; const float* wi; int wm;
  if (mode < 1024) { wr = wpr; wi = wpi; wm = mode; }
  else             { wr = wnr; wi = wni; wm = mode - 1024; }

  // issue all global loads early (latency overlapped across 4 blocks/CU)
  float2 xv[4];
#pragma unroll
  for (int j = 0; j < 4; ++j) {
    int bi = t + 256 * j;                        // b = bi>>6, i = bi&63
    xv[j] = X2[(size_t)bi * 2048 + mode];
  }
  float wre[16], wim[16];
#pragma unroll
  for (int k = 0; k < 16; ++k) {
    int io = t + 256 * k;                        // i = io>>6, o = io&63
    size_t a = (size_t)io * 1024 + wm;
    wre[k] = wr[a];
    wim[k] = wi[a];
  }
#pragma unroll
  for (int j = 0; j < 4; ++j) {
    int bi = t + 256 * j;
    Xs[bi >> 6][bi & 63] = xv[j];                // lanes: i consecutive -> conflict-free
  }
#pragma unroll
  for (int k = 0; k < 16; ++k) {
    int io = t + 256 * k;
    Wsh[io >> 6][io & 63] = make_float2(wre[k], wim[k]);
  }
  __syncthreads();

  const int o = t & 63, bg = t >> 6;             // bg wave-uniform
  float accr[4] = {0.f, 0.f, 0.f, 0.f};
  float acci[4] = {0.f, 0.f, 0.f, 0.f};
#pragma unroll 4
  for (int i = 0; i < 64; ++i) {
    float2 w = Wsh[i][o];
    float2 x0 = Xs[bg * 4 + 0][i];
    float2 x1 = Xs[bg * 4 + 1][i];
    float2 x2 = Xs[bg * 4 + 2][i];
    float2 x3 = Xs[bg * 4 + 3][i];
    accr[0] = fmaf(x0.x, w.x, fmaf(-x0.y, w.y, accr[0]));
    acci[0] = fmaf(x0.x, w.y, fmaf( x0.y, w.x, acci[0]));
    accr[1] = fmaf(x1.x, w.x, fmaf(-x1.y, w.y, accr[1]));
    acci[1] = fmaf(x1.x, w.y, fmaf( x1.y, w.x, acci[1]));
    accr[2] = fmaf(x2.x, w.x, fmaf(-x2.y, w.y, accr[2]));
    acci[2] = fmaf(x2.x, w.y, fmaf( x2.y, w.x, acci[2]));
    accr[3] = fmaf(x3.x, w.x, fmaf(-x3.y, w.y, accr[3]));
    acci[3] = fmaf(x3.x, w.y, fmaf( x3.y, w.x, acci[3]));
  }

  const float scale = (((mode & 31) == 0) ? 1.f : 2.f) * (1.f / 65536.f);
#pragma unroll
  for (int j = 0; j < 4; ++j) {
    int b = bg * 4 + j;
    Cc[(size_t)(b * 64 + o) * 2048 + mode] =
        make_float2(accr[j] * scale, acci[j] * scale);
  }
}

// ---------------- D: inverse y-DFT ----------------
// grid 1024 (b*64+o); block 256: thread = (h = hp*64 + t>>2, kx0 = (t&3)*8)
__global__ __launch_bounds__(256) void k_D(const float2* __restrict__ Cc,
                                           const float* __restrict__ twyT,
                                           float* __restrict__ Y1) {
  __shared__ float Cr[64][36], Ci[64][36];
  const int t = threadIdx.x, bo = blockIdx.x;
  const float4* Cp = (const float4*)(Cc + (size_t)bo * 2048);
#pragma unroll
  for (int j = 0; j < 4; ++j) {
    int f4 = t + 256 * j;
    float4 v = Cp[f4];
    int mode = f4 * 2;
    int mm = mode >> 5, kx = mode & 31;
    Cr[mm][kx]     = v.x; Ci[mm][kx]     = v.y;
    Cr[mm][kx + 1] = v.z; Ci[mm][kx + 1] = v.w;
  }
  __syncthreads();
  const int kx0 = (t & 3) * 8, hs = t >> 2;
  const float* cyp = twyT;
  const float* syp = twyT + 16384;
  for (int hp = 0; hp < 4; ++hp) {
    const int h = hp * 64 + hs;
    float accr[8] = {0,0,0,0,0,0,0,0};
    float accn[8] = {0,0,0,0,0,0,0,0};
#pragma unroll 2
    for (int mm = 0; mm < 64; ++mm) {
      float cy = cyp[mm * 256 + h];
      float sy = syp[mm * 256 + h];
      float4 c0 = *((const float4*)&Cr[mm][kx0]);
      float4 c1 = *((const float4*)&Cr[mm][kx0 + 4]);
      float4 d0 = *((const float4*)&Ci[mm][kx0]);
      float4 d1 = *((const float4*)&Ci[mm][kx0 + 4]);
      // Y = sum C * (cy + i sy):  re = Cr*cy - Ci*sy ; store neg-im = -(Cr*sy + Ci*cy)
#define DMAC(j, rr, ii)                                       \
      accr[j] = fmaf(rr, cy, fmaf(-(ii), sy, accr[j]));       \
      accn[j] = fmaf(-(rr), sy, fmaf(-(ii), cy, accn[j]));
      DMAC(0, c0.x, d0.x) DMAC(1, c0.y, d0.y)
      DMAC(2, c0.z, d0.z) DMAC(3, c0.w, d0.w)
      DMAC(4, c1.x, d1.x) DMAC(5, c1.y, d1.y)
      DMAC(6, c1.z, d1.z) DMAC(7, c1.w, d1.w)
#undef DMAC
    }
    float* dst = Y1 + (size_t)bo * 16384 + (size_t)h * 64 + kx0;
    *((float4*)(dst + 0))  = make_float4(accr[0], accr[1], accr[2], accr[3]);
    *((float4*)(dst + 4))  = make_float4(accr[4], accr[5], accr[6], accr[7]);
    *((float4*)(dst + 32)) = make_float4(accn[0], accn[1], accn[2], accn[3]);
    *((float4*)(dst + 36)) = make_float4(accn[4], accn[5], accn[6], accn[7]);
  }
}

// ---------------- E: inverse x-DFT + Re() ----------------
// grid 8192 row-tiles of 32; block 256: thread = (w = (t&63)*4, rows (t>>6)*8..)
__global__ __launch_bounds__(256) void k_E(const float* __restrict__ Y1,
                                           const float* __restrict__ twxT,
                                           float* __restrict__ out) {
  __shared__ float ys[32][68];
  const int t = threadIdx.x, blk = blockIdx.x;
  const float4* Yp = (const float4*)(Y1 + (size_t)blk * 2048);
#pragma unroll
  for (int j = 0; j < 2; ++j) {
    int f4 = t + 256 * j;
    int r = f4 >> 4, c4 = f4 & 15;
    *((float4*)&ys[r][c4 * 4]) = Yp[f4];
  }
  __syncthreads();
  const int wg = t & 63, rg = t >> 6;
  float acc[8][4];
#pragma unroll
  for (int r = 0; r < 8; ++r) {
    acc[r][0] = 0.f; acc[r][1] = 0.f; acc[r][2] = 0.f; acc[r][3] = 0.f;
  }
  const float4* twp = (const float4*)twxT;
#pragma unroll 2
  for (int k = 0; k < 64; ++k) {
    float4 tw = twp[k * 64 + wg];
#pragma unroll
    for (int r = 0; r < 8; ++r) {
      float yv = ys[rg * 8 + r][k];   // wave-uniform rg -> pure LDS broadcast
      acc[r][0] = fmaf(yv, tw.x, acc[r][0]);
      acc[r][1] = fmaf(yv, tw.y, acc[r][1]);
      acc[r][2] = fmaf(yv, tw.z, acc[r][2]);
      acc[r][3] = fmaf(yv, tw.w, acc[r][3]);
    }
  }
#pragma unroll
  for (int r = 0; r < 8; ++r) {
    size_t row = (size_t)blk * 32 + rg * 8 + r;
    *((float4*)(out + row * 256 + wg * 4)) =
        make_float4(acc[r][0], acc[r][1], acc[r][2], acc[r][3]);
  }
}

extern "C" void kernel_launch(void* const* d_in, const int* in_sizes, int n_in,
                              void* d_out, int out_size, void* d_ws, size_t ws_size,
                              hipStream_t stream) {
  (void)in_sizes; (void)n_in; (void)out_size; (void)ws_size;
  const float* x   = (const float*)d_in[0];
  const float* wpr = (const float*)d_in[1];
  const float* wpi = (const float*)d_in[2];
  const float* wnr = (const float*)d_in[3];
  const float* wni = (const float*)d_in[4];
  float* out = (float*)d_out;
  float* ws  = (float*)d_ws;

  // scratch inside d_out (fully overwritten by k_E at the end):
  float*  A1 = out;                                   // [1024][256][64]   = 16.78M f
  float2* X2 = (float2*)(out + 16777216);             // [1024][2048] f2   =  4.19M f
  float2* Cc = (float2*)(out + 16777216 + 4194304);   // [1024][2048] f2   =  4.19M f
  float*  Y1 = ws + T_Y1;                             // [1024][256][64]   = 16.78M f

  k_prep<<<384, 256, 0, stream>>>(ws);
  k_A<<<4096, 256, 0, stream>>>(x, ws + T_TWXA, A1);
  k_B<<<1024, 256, 0, stream>>>(A1, ws + T_TWYB, X2);
  k_C<<<2048, 256, 0, stream>>>(X2, wpr, wpi, wnr, wni, Cc);
  k_D<<<1024, 256, 0, stream>>>(Cc, ws + T_TWYT, Y1);
  k_E<<<8192, 256, 0, stream>>>(Y1, ws + T_TWXT, out);
}